// Round 2
// baseline (1136.422 us; speedup 1.0000x reference)
//
#include <hip/hip_runtime.h>

#define NN 50000
#define NE 800000
#define DD 128

// ---------------------------------------------------------------------------
// Edge messages: msg[e, b*4+o] = (sum_i h[src, b*4+i] * W[type, b*16+i*4+o]) * enorm[e]
// scattered with atomicAdd into agg[dst, :]. 2 edges per 256-thread block,
// 128 threads per edge (one per output element).
// ---------------------------------------------------------------------------
__global__ __launch_bounds__(256) void edge_msg(
    const float* __restrict__ x,      // [NN,DD] layer input
    const int*   __restrict__ esrc,
    const int*   __restrict__ edst,
    const int*   __restrict__ etyp,
    const float* __restrict__ enorm,  // [NE]
    const float* __restrict__ W,      // [460,512]
    float*       __restrict__ agg)    // [NN,DD] pre-zeroed, atomic accumulate
{
    const int t  = threadIdx.x;
    const int le = t >> 7;            // local edge 0/1 (wave-uniform)
    const int j  = t & 127;           // output element
    const int e  = blockIdx.x * 2 + le;

    __shared__ float sh[2][DD];
    const int src = esrc[e];
    sh[le][j] = x[(size_t)src * DD + j];
    __syncthreads();

    const int b = j >> 2;
    const int o = j & 3;
    const float* wr = W + (size_t)etyp[e] * 512 + b * 16 + o;
    const float4 hv = *(const float4*)&sh[le][b * 4];

    float m = hv.x * wr[0] + hv.y * wr[4] + hv.z * wr[8] + hv.w * wr[12];
    m *= enorm[e];
    atomicAdd(&agg[(size_t)edst[e] * DD + j], m);
}

// ---------------------------------------------------------------------------
// Combine: out[n,j] = relu?( out[n,j]*nnorm[n] + sum_k x[n,k]*lw[k,j]
//                            + sum_k (prev[n,k]*decay[n])*tw[k,j] )
// 8 nodes per 256-thread block; thread = (col j, half r); 4 nodes per thread.
// Weight reads are coalesced and read exactly once per block (128 KB/block
// from L2). h/prev rows staged in LDS, read as float4 broadcasts.
// ---------------------------------------------------------------------------
template<int ACT>
__global__ __launch_bounds__(256) void combine(
    float*       __restrict__ out,    // [NN,DD] in: agg, out: final
    const float* __restrict__ x,      // layer input to loop matmul
    const float* __restrict__ prev,
    const float* __restrict__ tdiff,  // [NN]
    const float* __restrict__ nnorm,  // [NN]
    const float* __restrict__ lw,     // [DD,DD]
    const float* __restrict__ tw)     // [DD,DD]
{
    const int t    = threadIdx.x;
    const int j    = t & 127;
    const int r    = t >> 7;          // 0/1
    const int base = blockIdx.x * 8;

    __shared__ float sh[8][DD];
    __shared__ float sp[8][DD];

    #pragma unroll
    for (int q = 0; q < 4; ++q) {
        const int m = q * 2 + r;
        const int n = base + m;
        const float decay = __expf(-tdiff[n] * 0.1f);
        sh[m][j] = x[(size_t)n * DD + j];
        sp[m][j] = prev[(size_t)n * DD + j] * decay;
    }
    __syncthreads();

    float acc[4] = {0.f, 0.f, 0.f, 0.f};
    for (int k = 0; k < DD; k += 4) {
        float wl[4], wt[4];
        #pragma unroll
        for (int kk = 0; kk < 4; ++kk) {
            wl[kk] = lw[(size_t)(k + kk) * DD + j];
            wt[kk] = tw[(size_t)(k + kk) * DD + j];
        }
        #pragma unroll
        for (int q = 0; q < 4; ++q) {
            const int m = q * 2 + r;
            const float4 a = *(const float4*)&sh[m][k];
            const float4 p = *(const float4*)&sp[m][k];
            acc[q] += a.x * wl[0] + a.y * wl[1] + a.z * wl[2] + a.w * wl[3]
                    + p.x * wt[0] + p.y * wt[1] + p.z * wt[2] + p.w * wt[3];
        }
    }

    #pragma unroll
    for (int q = 0; q < 4; ++q) {
        const int m = q * 2 + r;
        const int n = base + m;
        float v = out[(size_t)n * DD + j] * nnorm[n] + acc[q];
        if (ACT) v = fmaxf(v, 0.f);
        out[(size_t)n * DD + j] = v;
    }
}

extern "C" void kernel_launch(void* const* d_in, const int* in_sizes, int n_in,
                              void* d_out, int out_size, void* d_ws, size_t ws_size,
                              hipStream_t stream) {
    const float* h     = (const float*)d_in[0];
    const float* fprev = (const float*)d_in[1];
    const float* sprev = (const float*)d_in[2];
    const float* tdiff = (const float*)d_in[3];
    const int*   esrc  = (const int*)d_in[4];
    const int*   edst  = (const int*)d_in[5];
    const int*   etyp  = (const int*)d_in[6];
    const float* enorm = (const float*)d_in[7];
    const float* nnorm = (const float*)d_in[8];
    const float* W1    = (const float*)d_in[9];
    const float* W2    = (const float*)d_in[10];
    const float* lw1   = (const float*)d_in[11];
    const float* lw2   = (const float*)d_in[12];
    const float* tw1   = (const float*)d_in[13];
    const float* tw2   = (const float*)d_in[14];

    float* h1 = (float*)d_out;
    float* h2 = h1 + (size_t)NN * DD;

    const size_t layer_bytes = (size_t)NN * DD * sizeof(float);

    // ---- layer 1 ----
    hipMemsetAsync(h1, 0, layer_bytes, stream);
    edge_msg<<<NE / 2, 256, 0, stream>>>(h, esrc, edst, etyp, enorm, W1, h1);
    combine<0><<<NN / 8, 256, 0, stream>>>(h1, h, fprev, tdiff, nnorm, lw1, tw1);

    // ---- layer 2 (reads h1 from d_out) ----
    hipMemsetAsync(h2, 0, layer_bytes, stream);
    edge_msg<<<NE / 2, 256, 0, stream>>>(h1, esrc, edst, etyp, enorm, W2, h2);
    combine<1><<<NN / 8, 256, 0, stream>>>(h2, h1, sprev, tdiff, nnorm, lw2, tw2);
}

// Round 4
// 639.138 us; speedup vs baseline: 1.7781x; 1.7781x over previous
//
#include <hip/hip_runtime.h>

#define NN 50000
#define NE 800000
#define DD 128
#define NPAD 50176          // 196*256, padded scan domain
#define NBLK_SCAN 196       // NPAD/256

// ---------------------------------------------------------------------------
// ws layout (when ws_size permits):
//   int   cnt [NPAD]
//   int   off [NPAD]      (exclusive prefix of cnt; off[i]=NE for i>=NN)
//   int   cur [NPAD]      (running cursors, init = off)
//   int   bsum[256]       (per-block sums for scan)
//   int2  ssrc_type[NE]   (dst-sorted (src,type))
//   float snorm[NE]       (dst-sorted edge_norm)
// ---------------------------------------------------------------------------

__global__ __launch_bounds__(256) void k_hist(
    const int* __restrict__ edst, int* __restrict__ cnt)
{
    const int e = blockIdx.x * 256 + threadIdx.x;   // grid sized exactly NE/256
    atomicAdd(&cnt[edst[e]], 1);
}

__global__ __launch_bounds__(256) void k_scan_a(
    const int* __restrict__ cnt, int* __restrict__ bsum)
{
    __shared__ int s[256];
    const int t = threadIdx.x;
    s[t] = cnt[blockIdx.x * 256 + t];
    __syncthreads();
    for (int d = 128; d > 0; d >>= 1) {
        if (t < d) s[t] += s[t + d];
        __syncthreads();
    }
    if (t == 0) bsum[blockIdx.x] = s[0];
}

__global__ __launch_bounds__(256) void k_scan_b(int* __restrict__ bsum)
{
    __shared__ int s[256];
    const int t = threadIdx.x;
    s[t] = (t < NBLK_SCAN) ? bsum[t] : 0;
    __syncthreads();
    // Hillis-Steele inclusive scan
    for (int d = 1; d < 256; d <<= 1) {
        int v = (t >= d) ? s[t - d] : 0;
        __syncthreads();
        s[t] += v;
        __syncthreads();
    }
    // store exclusive
    bsum[t] = (t == 0) ? 0 : s[t - 1];
}

__global__ __launch_bounds__(256) void k_scan_c(
    const int* __restrict__ cnt, const int* __restrict__ bsum,
    int* __restrict__ off, int* __restrict__ cur)
{
    __shared__ int s[256];
    const int t = threadIdx.x;
    const int i = blockIdx.x * 256 + t;
    const int c = cnt[i];
    s[t] = c;
    __syncthreads();
    for (int d = 1; d < 256; d <<= 1) {
        int v = (t >= d) ? s[t - d] : 0;
        __syncthreads();
        s[t] += v;
        __syncthreads();
    }
    const int ex = bsum[blockIdx.x] + s[t] - c;   // exclusive within grid
    off[i] = ex;
    cur[i] = ex;
}

__global__ __launch_bounds__(256) void k_scatter(
    const int* __restrict__ esrc, const int* __restrict__ edst,
    const int* __restrict__ etyp, const float* __restrict__ enorm,
    int* __restrict__ cur, int2* __restrict__ ssrc_type,
    float* __restrict__ snorm)
{
    const int e = blockIdx.x * 256 + threadIdx.x;
    const int pos = atomicAdd(&cur[edst[e]], 1);
    ssrc_type[pos] = make_int2(esrc[e], etyp[e]);
    snorm[pos] = enorm[e];
}

// ---------------------------------------------------------------------------
// Aggregate: one 64-lane wave per dst node. Lane-linear layout:
//   lower half: (b = lane>>2, i = lane&3) -> h idx = lane, W idx = t*512 + 4*lane
//   upper half: b' = b+16            -> h idx = 64+lane, W idx = t*512+256+4*lane
// acc4 per lane holds partials over o=0..3; one 4-lane xor-reduce at the end;
// lane then writes out[j=lane] and out[j=64+lane] (coalesced, no atomics).
// ---------------------------------------------------------------------------
__device__ __forceinline__ float pick4(float4 v, int o) {
    float a = (o & 1) ? v.y : v.x;
    float b = (o & 1) ? v.w : v.z;
    return (o & 2) ? b : a;
}

__global__ __launch_bounds__(256) void k_agg(
    const float* __restrict__ x,          // [NN,DD]
    const int2*  __restrict__ ssrc_type,
    const float* __restrict__ snorm,
    const int*   __restrict__ off,
    const float* __restrict__ W,          // [460,512]
    float*       __restrict__ agg)        // [NN,DD] written fully, no memset needed
{
    const int lane = threadIdx.x & 63;
    const int n    = blockIdx.x * 4 + (threadIdx.x >> 6);

    const int beg = off[n];
    const int end = off[n + 1];

    float4 acca = make_float4(0.f, 0.f, 0.f, 0.f);
    float4 accb = make_float4(0.f, 0.f, 0.f, 0.f);

    for (int i = beg; i < end; ++i) {
        const int2  st = ssrc_type[i];
        const float nr = snorm[i];
        const float* wr = W + (size_t)st.y * 512 + 4 * lane;
        const float4 wa = *(const float4*)wr;
        const float4 wb = *(const float4*)(wr + 256);
        const float* hr = x + (size_t)st.x * DD;
        const float ha = hr[lane] * nr;
        const float hb = hr[64 + lane] * nr;
        acca.x += ha * wa.x; acca.y += ha * wa.y; acca.z += ha * wa.z; acca.w += ha * wa.w;
        accb.x += hb * wb.x; accb.y += hb * wb.y; accb.z += hb * wb.z; accb.w += hb * wb.w;
    }

    // reduce over i (4-lane groups): lanes b*4+i, i=0..3
    #pragma unroll
    for (int d = 1; d <= 2; d <<= 1) {
        acca.x += __shfl_xor(acca.x, d); acca.y += __shfl_xor(acca.y, d);
        acca.z += __shfl_xor(acca.z, d); acca.w += __shfl_xor(acca.w, d);
        accb.x += __shfl_xor(accb.x, d); accb.y += __shfl_xor(accb.y, d);
        accb.z += __shfl_xor(accb.z, d); accb.w += __shfl_xor(accb.w, d);
    }

    const int o = lane & 3;
    agg[(size_t)n * DD + lane]      = pick4(acca, o);
    agg[(size_t)n * DD + 64 + lane] = pick4(accb, o);
}

// ---------------------------------------------------------------------------
// Fallback atomic edge kernel (used only if ws_size is too small)
// ---------------------------------------------------------------------------
__global__ __launch_bounds__(256) void edge_msg(
    const float* __restrict__ x, const int* __restrict__ esrc,
    const int* __restrict__ edst, const int* __restrict__ etyp,
    const float* __restrict__ enorm, const float* __restrict__ W,
    float* __restrict__ agg)
{
    const int t  = threadIdx.x;
    const int le = t >> 7;
    const int j  = t & 127;
    const int e  = blockIdx.x * 2 + le;

    __shared__ float sh[2][DD];
    sh[le][j] = x[(size_t)esrc[e] * DD + j];
    __syncthreads();

    const int b = j >> 2;
    const int o = j & 3;
    const float* wr = W + (size_t)etyp[e] * 512 + b * 16 + o;
    const float4 hv = *(const float4*)&sh[le][b * 4];
    float m = hv.x * wr[0] + hv.y * wr[4] + hv.z * wr[8] + hv.w * wr[12];
    m *= enorm[e];
    atomicAdd(&agg[(size_t)edst[e] * DD + j], m);
}

// ---------------------------------------------------------------------------
// Combine (unchanged from round 2)
// ---------------------------------------------------------------------------
template<int ACT>
__global__ __launch_bounds__(256) void combine(
    float*       __restrict__ out,
    const float* __restrict__ x,
    const float* __restrict__ prev,
    const float* __restrict__ tdiff,
    const float* __restrict__ nnorm,
    const float* __restrict__ lw,
    const float* __restrict__ tw)
{
    const int t    = threadIdx.x;
    const int j    = t & 127;
    const int r    = t >> 7;
    const int base = blockIdx.x * 8;

    __shared__ float sh[8][DD];
    __shared__ float sp[8][DD];

    #pragma unroll
    for (int q = 0; q < 4; ++q) {
        const int m = q * 2 + r;
        const int n = base + m;
        const float decay = __expf(-tdiff[n] * 0.1f);
        sh[m][j] = x[(size_t)n * DD + j];
        sp[m][j] = prev[(size_t)n * DD + j] * decay;
    }
    __syncthreads();

    float acc[4] = {0.f, 0.f, 0.f, 0.f};
    for (int k = 0; k < DD; k += 4) {
        float wl[4], wt[4];
        #pragma unroll
        for (int kk = 0; kk < 4; ++kk) {
            wl[kk] = lw[(size_t)(k + kk) * DD + j];
            wt[kk] = tw[(size_t)(k + kk) * DD + j];
        }
        #pragma unroll
        for (int q = 0; q < 4; ++q) {
            const int m = q * 2 + r;
            const float4 a = *(const float4*)&sh[m][k];
            const float4 p = *(const float4*)&sp[m][k];
            acc[q] += a.x * wl[0] + a.y * wl[1] + a.z * wl[2] + a.w * wl[3]
                    + p.x * wt[0] + p.y * wt[1] + p.z * wt[2] + p.w * wt[3];
        }
    }

    #pragma unroll
    for (int q = 0; q < 4; ++q) {
        const int m = q * 2 + r;
        const int n = base + m;
        float v = out[(size_t)n * DD + j] * nnorm[n] + acc[q];
        if (ACT) v = fmaxf(v, 0.f);
        out[(size_t)n * DD + j] = v;
    }
}

extern "C" void kernel_launch(void* const* d_in, const int* in_sizes, int n_in,
                              void* d_out, int out_size, void* d_ws, size_t ws_size,
                              hipStream_t stream) {
    const float* h     = (const float*)d_in[0];
    const float* fprev = (const float*)d_in[1];
    const float* sprev = (const float*)d_in[2];
    const float* tdiff = (const float*)d_in[3];
    const int*   esrc  = (const int*)d_in[4];
    const int*   edst  = (const int*)d_in[5];
    const int*   etyp  = (const int*)d_in[6];
    const float* enorm = (const float*)d_in[7];
    const float* nnorm = (const float*)d_in[8];
    const float* W1    = (const float*)d_in[9];
    const float* W2    = (const float*)d_in[10];
    const float* lw1   = (const float*)d_in[11];
    const float* lw2   = (const float*)d_in[12];
    const float* tw1   = (const float*)d_in[13];
    const float* tw2   = (const float*)d_in[14];

    float* h1 = (float*)d_out;
    float* h2 = h1 + (size_t)NN * DD;
    const size_t layer_bytes = (size_t)NN * DD * sizeof(float);

    // carve workspace
    char* wsp = (char*)d_ws;
    int*   cnt       = (int*)wsp;                      wsp += (size_t)NPAD * 4;
    int*   off       = (int*)wsp;                      wsp += (size_t)NPAD * 4;
    int*   cur       = (int*)wsp;                      wsp += (size_t)NPAD * 4;
    int*   bsum      = (int*)wsp;                      wsp += 256 * 4;
    int2*  ssrc_type = (int2*)wsp;                     wsp += (size_t)NE * 8;
    float* snorm     = (float*)wsp;                    wsp += (size_t)NE * 4;
    const size_t ws_needed = (size_t)(wsp - (char*)d_ws);

    if (ws_size >= ws_needed) {
        // ---- one-time (per call) dst-sort of the edge list ----
        hipMemsetAsync(cnt, 0, (size_t)NPAD * 4, stream);
        k_hist   <<<NE / 256, 256, 0, stream>>>(edst, cnt);
        k_scan_a <<<NBLK_SCAN, 256, 0, stream>>>(cnt, bsum);
        k_scan_b <<<1, 256, 0, stream>>>(bsum);
        k_scan_c <<<NBLK_SCAN, 256, 0, stream>>>(cnt, bsum, off, cur);
        k_scatter<<<NE / 256, 256, 0, stream>>>(esrc, edst, etyp, enorm,
                                                cur, ssrc_type, snorm);

        // ---- layer 1 ----
        k_agg<<<NN / 4, 256, 0, stream>>>(h, ssrc_type, snorm, off, W1, h1);
        combine<0><<<NN / 8, 256, 0, stream>>>(h1, h, fprev, tdiff, nnorm, lw1, tw1);
        // ---- layer 2 ----
        k_agg<<<NN / 4, 256, 0, stream>>>(h1, ssrc_type, snorm, off, W2, h2);
        combine<1><<<NN / 8, 256, 0, stream>>>(h2, h1, sprev, tdiff, nnorm, lw2, tw2);
    } else {
        // fallback: atomic path
        hipMemsetAsync(h1, 0, layer_bytes, stream);
        edge_msg<<<NE / 2, 256, 0, stream>>>(h, esrc, edst, etyp, enorm, W1, h1);
        combine<0><<<NN / 8, 256, 0, stream>>>(h1, h, fprev, tdiff, nnorm, lw1, tw1);
        hipMemsetAsync(h2, 0, layer_bytes, stream);
        edge_msg<<<NE / 2, 256, 0, stream>>>(h1, esrc, edst, etyp, enorm, W2, h2);
        combine<1><<<NN / 8, 256, 0, stream>>>(h2, h1, sprev, tdiff, nnorm, lw2, tw2);
    }
}

// Round 5
// 522.608 us; speedup vs baseline: 2.1745x; 1.2230x over previous
//
#include <hip/hip_runtime.h>

#define NN 50000
#define NE 800000
#define DD 128
#define NPAD 50176          // 196*256, padded scan domain
#define NBLK_SCAN 196       // NPAD/256

typedef __attribute__((ext_vector_type(8))) short short8;
typedef __attribute__((ext_vector_type(4))) float f32x4;

static __device__ __forceinline__ float b2f(unsigned short u) {
    return __builtin_bit_cast(float, (unsigned)u << 16);
}
static __device__ __forceinline__ unsigned short f2b(float f) {
    unsigned u = __builtin_bit_cast(unsigned, f);
    u += 0x7FFFu + ((u >> 16) & 1u);          // round-to-nearest-even
    return (unsigned short)(u >> 16);
}

// ---------------------------------------------------------------------------
// dst-sort machinery (unchanged from round 4)
// ---------------------------------------------------------------------------
__global__ __launch_bounds__(256) void k_hist(
    const int* __restrict__ edst, int* __restrict__ cnt)
{
    const int e = blockIdx.x * 256 + threadIdx.x;
    atomicAdd(&cnt[edst[e]], 1);
}

__global__ __launch_bounds__(256) void k_scan_a(
    const int* __restrict__ cnt, int* __restrict__ bsum)
{
    __shared__ int s[256];
    const int t = threadIdx.x;
    s[t] = cnt[blockIdx.x * 256 + t];
    __syncthreads();
    for (int d = 128; d > 0; d >>= 1) {
        if (t < d) s[t] += s[t + d];
        __syncthreads();
    }
    if (t == 0) bsum[blockIdx.x] = s[0];
}

__global__ __launch_bounds__(256) void k_scan_b(int* __restrict__ bsum)
{
    __shared__ int s[256];
    const int t = threadIdx.x;
    s[t] = (t < NBLK_SCAN) ? bsum[t] : 0;
    __syncthreads();
    for (int d = 1; d < 256; d <<= 1) {
        int v = (t >= d) ? s[t - d] : 0;
        __syncthreads();
        s[t] += v;
        __syncthreads();
    }
    bsum[t] = (t == 0) ? 0 : s[t - 1];
}

__global__ __launch_bounds__(256) void k_scan_c(
    const int* __restrict__ cnt, const int* __restrict__ bsum,
    int* __restrict__ off, int* __restrict__ cur)
{
    __shared__ int s[256];
    const int t = threadIdx.x;
    const int i = blockIdx.x * 256 + t;
    const int c = cnt[i];
    s[t] = c;
    __syncthreads();
    for (int d = 1; d < 256; d <<= 1) {
        int v = (t >= d) ? s[t - d] : 0;
        __syncthreads();
        s[t] += v;
        __syncthreads();
    }
    const int ex = bsum[blockIdx.x] + s[t] - c;
    off[i] = ex;
    cur[i] = ex;
}

__global__ __launch_bounds__(256) void k_scatter(
    const int* __restrict__ esrc, const int* __restrict__ edst,
    const int* __restrict__ etyp, const float* __restrict__ enorm,
    int* __restrict__ cur, int2* __restrict__ ssrc_type,
    float* __restrict__ snorm)
{
    const int e = blockIdx.x * 256 + threadIdx.x;
    const int pos = atomicAdd(&cur[edst[e]], 1);
    ssrc_type[pos] = make_int2(esrc[e], etyp[e]);
    snorm[pos] = enorm[e];
}

// ---------------------------------------------------------------------------
// Conversions
// ---------------------------------------------------------------------------
// X1[n][0:128] = bf16(h), X1[n][128:256] = bf16(fprev*decay)
__global__ __launch_bounds__(256) void conv_x_full(
    const float* __restrict__ x, const float* __restrict__ prev,
    const float* __restrict__ tdiff, unsigned short* __restrict__ X)
{
    const int idx = blockIdx.x * 256 + threadIdx.x;   // 6.4M threads
    const int n = idx >> 7, j = idx & 127;
    const float d = __expf(-tdiff[n] * 0.1f);
    X[(size_t)n * 256 + j]       = f2b(x[(size_t)n * 128 + j]);
    X[(size_t)n * 256 + 128 + j] = f2b(prev[(size_t)n * 128 + j] * d);
}

// X2[n][128:256] = bf16(sprev*decay)  (left half filled by combine_mfma<...,1>)
__global__ __launch_bounds__(256) void conv_x_right(
    const float* __restrict__ prev, const float* __restrict__ tdiff,
    unsigned short* __restrict__ X)
{
    const int idx = blockIdx.x * 256 + threadIdx.x;
    const int n = idx >> 7, j = idx & 127;
    const float d = __expf(-tdiff[n] * 0.1f);
    X[(size_t)n * 256 + 128 + j] = f2b(prev[(size_t)n * 128 + j] * d);
}

// W [460,512] fp32 -> bf16
__global__ __launch_bounds__(256) void conv_w(
    const float* __restrict__ W, unsigned short* __restrict__ Wb)
{
    const int i = blockIdx.x * 256 + threadIdx.x;     // 235520 threads exact
    Wb[i] = f2b(W[i]);
}

// Pack Wc = [lw;tw] (256x128) into MFMA B-fragment order:
// chunk c = ct*512 + ks*64 + lane ; elem i: k = ks*32+(lane>>4)*8+i, col = ct*16+(lane&15)
__global__ __launch_bounds__(256) void pack_wc(
    const float* __restrict__ lw, const float* __restrict__ tw,
    unsigned short* __restrict__ Wp)
{
    const int c = blockIdx.x * 256 + threadIdx.x;     // 4096 chunks
    const int ct = c >> 9, ks = (c >> 6) & 7, lane = c & 63;
    const int col = ct * 16 + (lane & 15);
    unsigned short* o = Wp + (size_t)c * 8;
    #pragma unroll
    for (int i = 0; i < 8; ++i) {
        const int k = ks * 32 + (lane >> 4) * 8 + i;
        const float v = (k < 128) ? lw[(size_t)k * 128 + col]
                                  : tw[(size_t)(k - 128) * 128 + col];
        o[i] = f2b(v);
    }
}

// ---------------------------------------------------------------------------
// Aggregate (bf16 inputs, fp32 accumulate). One wave per dst node.
// x is the LEFT half of the bf16 X buffer (stride 256).
// ---------------------------------------------------------------------------
__device__ __forceinline__ float pick4(float4 v, int o) {
    float a = (o & 1) ? v.y : v.x;
    float b = (o & 1) ? v.w : v.z;
    return (o & 2) ? b : a;
}

__global__ __launch_bounds__(256) void k_agg_b(
    const unsigned short* __restrict__ x,    // [NN,256] bf16, cols 0..127 used
    const int2*  __restrict__ ssrc_type,
    const float* __restrict__ snorm,
    const int*   __restrict__ off,
    const unsigned short* __restrict__ Wb,   // [460,512] bf16
    float*       __restrict__ agg)           // [NN,128] fully written
{
    const int lane = threadIdx.x & 63;
    const int n    = blockIdx.x * 4 + (threadIdx.x >> 6);

    const int beg = off[n];
    const int end = off[n + 1];

    float4 acca = make_float4(0.f, 0.f, 0.f, 0.f);
    float4 accb = make_float4(0.f, 0.f, 0.f, 0.f);

    for (int i = beg; i < end; ++i) {
        const int2  st = ssrc_type[i];
        const float nr = snorm[i];
        const unsigned short* wr = Wb + (size_t)st.y * 512 + 4 * lane;
        const ushort4 wa = *(const ushort4*)wr;
        const ushort4 wb = *(const ushort4*)(wr + 256);
        const unsigned short* hr = x + (size_t)st.x * 256;
        const float ha = b2f(hr[lane]) * nr;
        const float hb = b2f(hr[64 + lane]) * nr;
        acca.x += ha * b2f(wa.x); acca.y += ha * b2f(wa.y);
        acca.z += ha * b2f(wa.z); acca.w += ha * b2f(wa.w);
        accb.x += hb * b2f(wb.x); accb.y += hb * b2f(wb.y);
        accb.z += hb * b2f(wb.z); accb.w += hb * b2f(wb.w);
    }

    #pragma unroll
    for (int d = 1; d <= 2; d <<= 1) {
        acca.x += __shfl_xor(acca.x, d); acca.y += __shfl_xor(acca.y, d);
        acca.z += __shfl_xor(acca.z, d); acca.w += __shfl_xor(acca.w, d);
        accb.x += __shfl_xor(accb.x, d); accb.y += __shfl_xor(accb.y, d);
        accb.z += __shfl_xor(accb.z, d); accb.w += __shfl_xor(accb.w, d);
    }

    const int o = lane & 3;
    agg[(size_t)n * DD + lane]      = pick4(acca, o);
    agg[(size_t)n * DD + 64 + lane] = pick4(accb, o);
}

// ---------------------------------------------------------------------------
// Fused GEMM-combine via MFMA:
//   out[n] = agg[n]*nnorm[n] + (X[n] @ Wc) [+relu] ; optionally bf16 copy -> Xnext left
// Block: 256 thr = 4 waves (wr,wc in 2x2); block tile 64 rows x 128 cols;
// wave tile 32x64 = 2 rowgroups x 4 coltiles of 16x16, K=256 in 8 steps of 32.
// A-frag: lane l holds X[row=base+(l&15)][k=ks*32+(l>>4)*8 + 0..7] (16B load).
// B-frag: pre-packed by pack_wc (16B load). C/D: col=l&15, row=(l>>4)*4+q (m89).
// ---------------------------------------------------------------------------
template<int ACT, int WRITE_NEXT>
__global__ __launch_bounds__(256) void combine_mfma(
    const float* __restrict__ agg,
    const unsigned short* __restrict__ X,     // [NN,256] bf16
    const unsigned short* __restrict__ Wp,    // packed 64KB
    const float* __restrict__ nnorm,
    float* __restrict__ out,                  // may alias agg (in-place safe)
    unsigned short* __restrict__ Xnext)       // [NN,256] bf16 or nullptr
{
    const int t = threadIdx.x;
    const int l = t & 63;
    const int w = t >> 6;
    const int wr = w >> 1, wc = w & 1;
    const int l15 = l & 15, lhi = l >> 4;
    const int rowbase = blockIdx.x * 64 + wr * 32;

    f32x4 acc[2][4] = {};

    const int ar0 = min(rowbase + l15, NN - 1);
    const int ar1 = min(rowbase + 16 + l15, NN - 1);
    const unsigned short* a0p = X + (size_t)ar0 * 256 + lhi * 8;
    const unsigned short* a1p = X + (size_t)ar1 * 256 + lhi * 8;
    const unsigned short* bp  = Wp + (size_t)(wc * 4) * 8 * 512 + (size_t)l * 8;

    #pragma unroll
    for (int ks = 0; ks < 8; ++ks) {
        const short8 a0 = *(const short8*)(a0p + ks * 32);
        const short8 a1 = *(const short8*)(a1p + ks * 32);
        #pragma unroll
        for (int ct = 0; ct < 4; ++ct) {
            const short8 b = *(const short8*)(bp + (size_t)(ct * 8 + ks) * 512);
            acc[0][ct] = __builtin_amdgcn_mfma_f32_16x16x32_bf16(a0, b, acc[0][ct], 0, 0, 0);
            acc[1][ct] = __builtin_amdgcn_mfma_f32_16x16x32_bf16(a1, b, acc[1][ct], 0, 0, 0);
        }
    }

    #pragma unroll
    for (int rg = 0; rg < 2; ++rg) {
        #pragma unroll
        for (int q = 0; q < 4; ++q) {
            const int row = rowbase + rg * 16 + lhi * 4 + q;
            if (row < NN) {
                const float nn = nnorm[row];
                #pragma unroll
                for (int ct = 0; ct < 4; ++ct) {
                    const int col = wc * 64 + ct * 16 + l15;
                    float v = agg[(size_t)row * DD + col] * nn + acc[rg][ct][q];
                    if (ACT) v = fmaxf(v, 0.f);
                    out[(size_t)row * DD + col] = v;
                    if (WRITE_NEXT) Xnext[(size_t)row * 256 + col] = f2b(v);
                }
            }
        }
    }
}

// ---------------------------------------------------------------------------
// Tier-2/3 fallback kernels (round-4 proven fp32 path)
// ---------------------------------------------------------------------------
__global__ __launch_bounds__(256) void k_agg(
    const float* __restrict__ x, const int2* __restrict__ ssrc_type,
    const float* __restrict__ snorm, const int* __restrict__ off,
    const float* __restrict__ W, float* __restrict__ agg)
{
    const int lane = threadIdx.x & 63;
    const int n    = blockIdx.x * 4 + (threadIdx.x >> 6);
    const int beg = off[n], end = off[n + 1];
    float4 acca = make_float4(0.f, 0.f, 0.f, 0.f);
    float4 accb = make_float4(0.f, 0.f, 0.f, 0.f);
    for (int i = beg; i < end; ++i) {
        const int2  st = ssrc_type[i];
        const float nr = snorm[i];
        const float* wr = W + (size_t)st.y * 512 + 4 * lane;
        const float4 wa = *(const float4*)wr;
        const float4 wb = *(const float4*)(wr + 256);
        const float* hr = x + (size_t)st.x * DD;
        const float ha = hr[lane] * nr;
        const float hb = hr[64 + lane] * nr;
        acca.x += ha * wa.x; acca.y += ha * wa.y; acca.z += ha * wa.z; acca.w += ha * wa.w;
        accb.x += hb * wb.x; accb.y += hb * wb.y; accb.z += hb * wb.z; accb.w += hb * wb.w;
    }
    #pragma unroll
    for (int d = 1; d <= 2; d <<= 1) {
        acca.x += __shfl_xor(acca.x, d); acca.y += __shfl_xor(acca.y, d);
        acca.z += __shfl_xor(acca.z, d); acca.w += __shfl_xor(acca.w, d);
        accb.x += __shfl_xor(accb.x, d); accb.y += __shfl_xor(accb.y, d);
        accb.z += __shfl_xor(accb.z, d); accb.w += __shfl_xor(accb.w, d);
    }
    const int o = lane & 3;
    agg[(size_t)n * DD + lane]      = pick4(acca, o);
    agg[(size_t)n * DD + 64 + lane] = pick4(accb, o);
}

__global__ __launch_bounds__(256) void edge_msg(
    const float* __restrict__ x, const int* __restrict__ esrc,
    const int* __restrict__ edst, const int* __restrict__ etyp,
    const float* __restrict__ enorm, const float* __restrict__ W,
    float* __restrict__ agg)
{
    const int t  = threadIdx.x;
    const int le = t >> 7;
    const int j  = t & 127;
    const int e  = blockIdx.x * 2 + le;
    __shared__ float sh[2][DD];
    sh[le][j] = x[(size_t)esrc[e] * DD + j];
    __syncthreads();
    const int b = j >> 2, o = j & 3;
    const float* wr = W + (size_t)etyp[e] * 512 + b * 16 + o;
    const float4 hv = *(const float4*)&sh[le][b * 4];
    float m = hv.x * wr[0] + hv.y * wr[4] + hv.z * wr[8] + hv.w * wr[12];
    m *= enorm[e];
    atomicAdd(&agg[(size_t)edst[e] * DD + j], m);
}

template<int ACT>
__global__ __launch_bounds__(256) void combine(
    float* __restrict__ out, const float* __restrict__ x,
    const float* __restrict__ prev, const float* __restrict__ tdiff,
    const float* __restrict__ nnorm, const float* __restrict__ lw,
    const float* __restrict__ tw)
{
    const int t = threadIdx.x;
    const int j = t & 127;
    const int r = t >> 7;
    const int base = blockIdx.x * 8;
    __shared__ float sh[8][DD];
    __shared__ float sp[8][DD];
    #pragma unroll
    for (int q = 0; q < 4; ++q) {
        const int m = q * 2 + r;
        const int n = base + m;
        const float decay = __expf(-tdiff[n] * 0.1f);
        sh[m][j] = x[(size_t)n * DD + j];
        sp[m][j] = prev[(size_t)n * DD + j] * decay;
    }
    __syncthreads();
    float acc[4] = {0.f, 0.f, 0.f, 0.f};
    for (int k = 0; k < DD; k += 4) {
        float wl[4], wt[4];
        #pragma unroll
        for (int kk = 0; kk < 4; ++kk) {
            wl[kk] = lw[(size_t)(k + kk) * DD + j];
            wt[kk] = tw[(size_t)(k + kk) * DD + j];
        }
        #pragma unroll
        for (int q = 0; q < 4; ++q) {
            const int m = q * 2 + r;
            const float4 a = *(const float4*)&sh[m][k];
            const float4 p = *(const float4*)&sp[m][k];
            acc[q] += a.x * wl[0] + a.y * wl[1] + a.z * wl[2] + a.w * wl[3]
                    + p.x * wt[0] + p.y * wt[1] + p.z * wt[2] + p.w * wt[3];
        }
    }
    #pragma unroll
    for (int q = 0; q < 4; ++q) {
        const int m = q * 2 + r;
        const int n = base + m;
        float v = out[(size_t)n * DD + j] * nnorm[n] + acc[q];
        if (ACT) v = fmaxf(v, 0.f);
        out[(size_t)n * DD + j] = v;
    }
}

// ---------------------------------------------------------------------------
extern "C" void kernel_launch(void* const* d_in, const int* in_sizes, int n_in,
                              void* d_out, int out_size, void* d_ws, size_t ws_size,
                              hipStream_t stream) {
    const float* h     = (const float*)d_in[0];
    const float* fprev = (const float*)d_in[1];
    const float* sprev = (const float*)d_in[2];
    const float* tdiff = (const float*)d_in[3];
    const int*   esrc  = (const int*)d_in[4];
    const int*   edst  = (const int*)d_in[5];
    const int*   etyp  = (const int*)d_in[6];
    const float* enorm = (const float*)d_in[7];
    const float* nnorm = (const float*)d_in[8];
    const float* W1    = (const float*)d_in[9];
    const float* W2    = (const float*)d_in[10];
    const float* lw1   = (const float*)d_in[11];
    const float* lw2   = (const float*)d_in[12];
    const float* tw1   = (const float*)d_in[13];
    const float* tw2   = (const float*)d_in[14];

    float* h1 = (float*)d_out;
    float* h2 = h1 + (size_t)NN * DD;
    const size_t layer_bytes = (size_t)NN * DD * sizeof(float);

    // ---- carve workspace ----
    char* wsp = (char*)d_ws;
    int*   cnt       = (int*)wsp;   wsp += (size_t)NPAD * 4;
    int*   off       = (int*)wsp;   wsp += (size_t)NPAD * 4;
    int*   cur       = (int*)wsp;   wsp += (size_t)NPAD * 4;
    int*   bsum      = (int*)wsp;   wsp += 256 * 4;
    int2*  ssrc_type = (int2*)wsp;  wsp += (size_t)NE * 8;
    float* snorm     = (float*)wsp; wsp += (size_t)NE * 4;
    const size_t ws_sorted = (size_t)(wsp - (char*)d_ws);
    unsigned short* X1   = (unsigned short*)wsp; wsp += (size_t)NN * 256 * 2;
    unsigned short* X2   = (unsigned short*)wsp; wsp += (size_t)NN * 256 * 2;
    unsigned short* Wc1p = (unsigned short*)wsp; wsp += 4096 * 8 * 2;
    unsigned short* Wc2p = (unsigned short*)wsp; wsp += 4096 * 8 * 2;
    unsigned short* W1b  = (unsigned short*)wsp; wsp += (size_t)460 * 512 * 2;
    unsigned short* W2b  = (unsigned short*)wsp; wsp += (size_t)460 * 512 * 2;
    const size_t ws_full = (size_t)(wsp - (char*)d_ws);

    const int grid_mm = (NN + 63) / 64;   // 782

    if (ws_size >= ws_full) {
        // ---- sort (shared by both layers) ----
        hipMemsetAsync(cnt, 0, (size_t)NPAD * 4, stream);
        k_hist   <<<NE / 256, 256, 0, stream>>>(edst, cnt);
        k_scan_a <<<NBLK_SCAN, 256, 0, stream>>>(cnt, bsum);
        k_scan_b <<<1, 256, 0, stream>>>(bsum);
        k_scan_c <<<NBLK_SCAN, 256, 0, stream>>>(cnt, bsum, off, cur);
        k_scatter<<<NE / 256, 256, 0, stream>>>(esrc, edst, etyp, enorm,
                                                cur, ssrc_type, snorm);
        // ---- conversions ----
        conv_x_full <<<NN * DD / 256, 256, 0, stream>>>(h, fprev, tdiff, X1);
        conv_x_right<<<NN * DD / 256, 256, 0, stream>>>(sprev, tdiff, X2);
        pack_wc<<<16, 256, 0, stream>>>(lw1, tw1, Wc1p);
        pack_wc<<<16, 256, 0, stream>>>(lw2, tw2, Wc2p);
        conv_w <<<460 * 512 / 256, 256, 0, stream>>>(W1, W1b);
        conv_w <<<460 * 512 / 256, 256, 0, stream>>>(W2, W2b);
        // ---- layer 1 ----
        k_agg_b<<<NN / 4, 256, 0, stream>>>(X1, ssrc_type, snorm, off, W1b, h1);
        combine_mfma<0, 1><<<grid_mm, 256, 0, stream>>>(h1, X1, Wc1p, nnorm, h1, X2);
        // ---- layer 2 ----
        k_agg_b<<<NN / 4, 256, 0, stream>>>(X2, ssrc_type, snorm, off, W2b, h2);
        combine_mfma<1, 0><<<grid_mm, 256, 0, stream>>>(h2, X2, Wc2p, nnorm, h2, nullptr);
    } else if (ws_size >= ws_sorted) {
        // tier 2: round-4 fp32 sorted path
        hipMemsetAsync(cnt, 0, (size_t)NPAD * 4, stream);
        k_hist   <<<NE / 256, 256, 0, stream>>>(edst, cnt);
        k_scan_a <<<NBLK_SCAN, 256, 0, stream>>>(cnt, bsum);
        k_scan_b <<<1, 256, 0, stream>>>(bsum);
        k_scan_c <<<NBLK_SCAN, 256, 0, stream>>>(cnt, bsum, off, cur);
        k_scatter<<<NE / 256, 256, 0, stream>>>(esrc, edst, etyp, enorm,
                                                cur, ssrc_type, snorm);
        k_agg<<<NN / 4, 256, 0, stream>>>(h, ssrc_type, snorm, off, W1, h1);
        combine<0><<<NN / 8, 256, 0, stream>>>(h1, h, fprev, tdiff, nnorm, lw1, tw1);
        k_agg<<<NN / 4, 256, 0, stream>>>(h1, ssrc_type, snorm, off, W2, h2);
        combine<1><<<NN / 8, 256, 0, stream>>>(h2, h1, sprev, tdiff, nnorm, lw2, tw2);
    } else {
        // tier 3: atomic path
        hipMemsetAsync(h1, 0, layer_bytes, stream);
        edge_msg<<<NE / 2, 256, 0, stream>>>(h, esrc, edst, etyp, enorm, W1, h1);
        combine<0><<<NN / 8, 256, 0, stream>>>(h1, h, fprev, tdiff, nnorm, lw1, tw1);
        hipMemsetAsync(h2, 0, layer_bytes, stream);
        edge_msg<<<NE / 2, 256, 0, stream>>>(h1, esrc, edst, etyp, enorm, W2, h2);
        combine<1><<<NN / 8, 256, 0, stream>>>(h2, h1, sprev, tdiff, nnorm, lw2, tw2);
    }
}

// Round 6
// 429.830 us; speedup vs baseline: 2.6439x; 1.2158x over previous
//
#include <hip/hip_runtime.h>

#define NN 50000
#define NE 800000
#define DD 128
#define NPAD 50176          // 196*256, padded scan domain
#define NBLK_SCAN 196       // NPAD/256

typedef __attribute__((ext_vector_type(8))) short short8;
typedef __attribute__((ext_vector_type(4))) float f32x4;

static __device__ __forceinline__ float b2f(unsigned short u) {
    return __builtin_bit_cast(float, (unsigned)u << 16);
}
static __device__ __forceinline__ float b2f_lo(unsigned u) {
    return __builtin_bit_cast(float, u << 16);
}
static __device__ __forceinline__ float b2f_hi(unsigned u) {
    return __builtin_bit_cast(float, u & 0xffff0000u);
}
static __device__ __forceinline__ unsigned short f2b(float f) {
    unsigned u = __builtin_bit_cast(unsigned, f);
    u += 0x7FFFu + ((u >> 16) & 1u);          // round-to-nearest-even
    return (unsigned short)(u >> 16);
}

// ---------------------------------------------------------------------------
// dst-sort machinery
// ---------------------------------------------------------------------------
__global__ __launch_bounds__(256) void k_hist(
    const int* __restrict__ edst, int* __restrict__ cnt)
{
    const int e = blockIdx.x * 256 + threadIdx.x;
    atomicAdd(&cnt[edst[e]], 1);
}

__global__ __launch_bounds__(256) void k_scan_a(
    const int* __restrict__ cnt, int* __restrict__ bsum)
{
    __shared__ int s[256];
    const int t = threadIdx.x;
    s[t] = cnt[blockIdx.x * 256 + t];
    __syncthreads();
    for (int d = 128; d > 0; d >>= 1) {
        if (t < d) s[t] += s[t + d];
        __syncthreads();
    }
    if (t == 0) bsum[blockIdx.x] = s[0];
}

__global__ __launch_bounds__(256) void k_scan_b(int* __restrict__ bsum)
{
    __shared__ int s[256];
    const int t = threadIdx.x;
    s[t] = (t < NBLK_SCAN) ? bsum[t] : 0;
    __syncthreads();
    for (int d = 1; d < 256; d <<= 1) {
        int v = (t >= d) ? s[t - d] : 0;
        __syncthreads();
        s[t] += v;
        __syncthreads();
    }
    bsum[t] = (t == 0) ? 0 : s[t - 1];
}

__global__ __launch_bounds__(256) void k_scan_c(
    const int* __restrict__ cnt, const int* __restrict__ bsum,
    int* __restrict__ off, int* __restrict__ cur)
{
    __shared__ int s[256];
    const int t = threadIdx.x;
    const int i = blockIdx.x * 256 + t;
    const int c = cnt[i];
    s[t] = c;
    __syncthreads();
    for (int d = 1; d < 256; d <<= 1) {
        int v = (t >= d) ? s[t - d] : 0;
        __syncthreads();
        s[t] += v;
        __syncthreads();
    }
    const int ex = bsum[blockIdx.x] + s[t] - c;
    off[i] = ex;
    cur[i] = ex;
}

// packed record: {src, typ, norm_bits, 0}
__global__ __launch_bounds__(256) void k_scatter(
    const int* __restrict__ esrc, const int* __restrict__ edst,
    const int* __restrict__ etyp, const float* __restrict__ enorm,
    int* __restrict__ cur, int4* __restrict__ sedge)
{
    const int e = blockIdx.x * 256 + threadIdx.x;
    const int pos = atomicAdd(&cur[edst[e]], 1);
    sedge[pos] = make_int4(esrc[e], etyp[e],
                           __builtin_bit_cast(int, enorm[e]), 0);
}

// ---------------------------------------------------------------------------
// Conversions (fused)
// ---------------------------------------------------------------------------
// X1[n][0:128]=bf16(h); X1[n][128:256]=bf16(fprev*d); X2[n][128:256]=bf16(sprev*d)
__global__ __launch_bounds__(256) void conv_x(
    const float* __restrict__ x, const float* __restrict__ fprev,
    const float* __restrict__ sprev, const float* __restrict__ tdiff,
    unsigned short* __restrict__ X1, unsigned short* __restrict__ X2)
{
    const int idx = blockIdx.x * 256 + threadIdx.x;   // NN*128 threads
    const int n = idx >> 7, j = idx & 127;
    const float d = __expf(-tdiff[n] * 0.1f);
    X1[(size_t)n * 256 + j]       = f2b(x[(size_t)n * 128 + j]);
    X1[(size_t)n * 256 + 128 + j] = f2b(fprev[(size_t)n * 128 + j] * d);
    X2[(size_t)n * 256 + 128 + j] = f2b(sprev[(size_t)n * 128 + j] * d);
}

// both W tensors fp32 -> bf16 (i in [0, 2*460*512))
__global__ __launch_bounds__(256) void conv_w2(
    const float* __restrict__ W1, const float* __restrict__ W2,
    unsigned short* __restrict__ W1b, unsigned short* __restrict__ W2b)
{
    const int i = blockIdx.x * 256 + threadIdx.x;
    if (i < 460 * 512) W1b[i] = f2b(W1[i]);
    else               W2b[i - 460 * 512] = f2b(W2[i - 460 * 512]);
}

// Pack Wc = [lw;tw] (256x128) into MFMA B-fragment order, both layers.
// chunk c = ct*512 + ks*64 + lane ; elem i: k = ks*32+(lane>>4)*8+i, col = ct*16+(lane&15)
__global__ __launch_bounds__(256) void pack_wc2(
    const float* __restrict__ lw1, const float* __restrict__ tw1,
    const float* __restrict__ lw2, const float* __restrict__ tw2,
    unsigned short* __restrict__ Wp1, unsigned short* __restrict__ Wp2)
{
    const int g = blockIdx.x * 256 + threadIdx.x;     // 8192
    const int c = g & 4095;
    const float* lw = (g < 4096) ? lw1 : lw2;
    const float* tw = (g < 4096) ? tw1 : tw2;
    unsigned short* Wp = (g < 4096) ? Wp1 : Wp2;
    const int ct = c >> 9, ks = (c >> 6) & 7, lane = c & 63;
    const int col = ct * 16 + (lane & 15);
    unsigned short* o = Wp + (size_t)c * 8;
    #pragma unroll
    for (int i = 0; i < 8; ++i) {
        const int k = ks * 32 + (lane >> 4) * 8 + i;
        const float v = (k < 128) ? lw[(size_t)k * 128 + col]
                                  : tw[(size_t)(k - 128) * 128 + col];
        o[i] = f2b(v);
    }
}

// ---------------------------------------------------------------------------
// Aggregate v2: one wave per dst node, lane l handles k in {2l, 2l+1}
// (always the same 4-wide diag-block). Per edge: 1 dwordx4 meta (scalarized),
// 1 dwordx4 W (64 lanes cover the whole 1KB row), 1 dword h (coalesced row).
// 4-deep unroll, independent accumulators. Writes agg*nnorm.
// ---------------------------------------------------------------------------
__device__ __forceinline__ void agg_edge(
    const unsigned short* __restrict__ x,
    const unsigned short* __restrict__ Wb,
    const int4* __restrict__ sedge, int i,
    int woff, int l, float4& acc)
{
    const int4 e = sedge[i];
    const int src = __builtin_amdgcn_readfirstlane(e.x);
    const int typ = __builtin_amdgcn_readfirstlane(e.y);
    const float nr = __builtin_bit_cast(float, __builtin_amdgcn_readfirstlane(e.z));
    const unsigned hw = ((const unsigned*)(x + (size_t)src * 256))[l];
    const uint4 wv = *(const uint4*)(Wb + (size_t)typ * 512 + woff);
    const float h0 = b2f_lo(hw) * nr;
    const float h1 = b2f_hi(hw) * nr;
    acc.x += h0 * b2f_lo(wv.x) + h1 * b2f_lo(wv.z);
    acc.y += h0 * b2f_hi(wv.x) + h1 * b2f_hi(wv.z);
    acc.z += h0 * b2f_lo(wv.y) + h1 * b2f_lo(wv.w);
    acc.w += h0 * b2f_hi(wv.y) + h1 * b2f_hi(wv.w);
}

__global__ __launch_bounds__(256) void k_agg2(
    const unsigned short* __restrict__ x,    // [NN,256] bf16, cols 0..127 used
    const int4*  __restrict__ sedge,
    const int*   __restrict__ off,
    const unsigned short* __restrict__ Wb,   // [460,512] bf16
    const float* __restrict__ nnorm,
    float*       __restrict__ agg)           // [NN,128] = sum * nnorm
{
    const int l = threadIdx.x & 63;
    const int n = blockIdx.x * 4 + (threadIdx.x >> 6);
    const int beg = off[n], end = off[n + 1];
    const int woff = (l >> 1) * 16 + (l & 1) * 8;   // ushort offset in W row

    float4 a0 = {0,0,0,0}, a1 = {0,0,0,0}, a2 = {0,0,0,0}, a3 = {0,0,0,0};

    int i = beg;
    for (; i + 4 <= end; i += 4) {
        agg_edge(x, Wb, sedge, i,     woff, l, a0);
        agg_edge(x, Wb, sedge, i + 1, woff, l, a1);
        agg_edge(x, Wb, sedge, i + 2, woff, l, a2);
        agg_edge(x, Wb, sedge, i + 3, woff, l, a3);
    }
    for (; i < end; ++i) agg_edge(x, Wb, sedge, i, woff, l, a0);

    float4 s;
    s.x = (a0.x + a1.x) + (a2.x + a3.x);
    s.y = (a0.y + a1.y) + (a2.y + a3.y);
    s.z = (a0.z + a1.z) + (a2.z + a3.z);
    s.w = (a0.w + a1.w) + (a2.w + a3.w);
    s.x += __shfl_xor(s.x, 1);
    s.y += __shfl_xor(s.y, 1);
    s.z += __shfl_xor(s.z, 1);
    s.w += __shfl_xor(s.w, 1);

    const float nn = nnorm[n];
    const float e0 = (l & 1) ? s.z : s.x;
    const float e1 = (l & 1) ? s.w : s.y;
    float2* outp = (float2*)(agg + (size_t)n * DD + (l >> 1) * 4 + (l & 1) * 2);
    *outp = make_float2(e0 * nn, e1 * nn);
}

// ---------------------------------------------------------------------------
// Fused GEMM-combine via MFMA (agg already nnorm-scaled):
//   out[n] = agg[n] + (X[n] @ Wc) [+relu] ; optionally bf16 copy -> Xnext left
// ---------------------------------------------------------------------------
template<int ACT, int WRITE_NEXT>
__global__ __launch_bounds__(256) void combine_mfma(
    const float* __restrict__ agg,
    const unsigned short* __restrict__ X,     // [NN,256] bf16
    const unsigned short* __restrict__ Wp,    // packed 64KB
    float* __restrict__ out,                  // may alias agg
    unsigned short* __restrict__ Xnext)       // [NN,256] bf16 or nullptr
{
    const int t = threadIdx.x;
    const int l = t & 63;
    const int w = t >> 6;
    const int wr = w >> 1, wc = w & 1;
    const int l15 = l & 15, lhi = l >> 4;
    const int rowbase = blockIdx.x * 64 + wr * 32;

    f32x4 acc[2][4] = {};

    const int ar0 = min(rowbase + l15, NN - 1);
    const int ar1 = min(rowbase + 16 + l15, NN - 1);
    const unsigned short* a0p = X + (size_t)ar0 * 256 + lhi * 8;
    const unsigned short* a1p = X + (size_t)ar1 * 256 + lhi * 8;
    const unsigned short* bp  = Wp + (size_t)(wc * 4) * 8 * 512 + (size_t)l * 8;

    #pragma unroll
    for (int ks = 0; ks < 8; ++ks) {
        const short8 a0 = *(const short8*)(a0p + ks * 32);
        const short8 a1 = *(const short8*)(a1p + ks * 32);
        #pragma unroll
        for (int ct = 0; ct < 4; ++ct) {
            const short8 b = *(const short8*)(bp + (size_t)(ct * 8 + ks) * 512);
            acc[0][ct] = __builtin_amdgcn_mfma_f32_16x16x32_bf16(a0, b, acc[0][ct], 0, 0, 0);
            acc[1][ct] = __builtin_amdgcn_mfma_f32_16x16x32_bf16(a1, b, acc[1][ct], 0, 0, 0);
        }
    }

    #pragma unroll
    for (int rg = 0; rg < 2; ++rg) {
        #pragma unroll
        for (int q = 0; q < 4; ++q) {
            const int row = rowbase + rg * 16 + lhi * 4 + q;
            if (row < NN) {
                #pragma unroll
                for (int ct = 0; ct < 4; ++ct) {
                    const int col = wc * 64 + ct * 16 + l15;
                    float v = agg[(size_t)row * DD + col] + acc[rg][ct][q];
                    if (ACT) v = fmaxf(v, 0.f);
                    out[(size_t)row * DD + col] = v;
                    if (WRITE_NEXT) Xnext[(size_t)row * 256 + col] = f2b(v);
                }
            }
        }
    }
}

// ---------------------------------------------------------------------------
// Tier-2 fp32 aggregate on packed records (writes agg WITHOUT nnorm; tier-2
// combine applies nnorm) and tier-2/3 combine + tier-3 atomic kernel.
// ---------------------------------------------------------------------------
__device__ __forceinline__ float pick4(float4 v, int o) {
    float a = (o & 1) ? v.y : v.x;
    float b = (o & 1) ? v.w : v.z;
    return (o & 2) ? b : a;
}

__global__ __launch_bounds__(256) void k_agg_t2(
    const float* __restrict__ x, const int4* __restrict__ sedge,
    const int* __restrict__ off, const float* __restrict__ W,
    float* __restrict__ agg)
{
    const int lane = threadIdx.x & 63;
    const int n    = blockIdx.x * 4 + (threadIdx.x >> 6);
    const int beg = off[n], end = off[n + 1];
    float4 acca = make_float4(0.f, 0.f, 0.f, 0.f);
    float4 accb = make_float4(0.f, 0.f, 0.f, 0.f);
    for (int i = beg; i < end; ++i) {
        const int4 e = sedge[i];
        const float nr = __builtin_bit_cast(float, e.z);
        const float* wr = W + (size_t)e.y * 512 + 4 * lane;
        const float4 wa = *(const float4*)wr;
        const float4 wb = *(const float4*)(wr + 256);
        const float* hr = x + (size_t)e.x * DD;
        const float ha = hr[lane] * nr;
        const float hb = hr[64 + lane] * nr;
        acca.x += ha * wa.x; acca.y += ha * wa.y; acca.z += ha * wa.z; acca.w += ha * wa.w;
        accb.x += hb * wb.x; accb.y += hb * wb.y; accb.z += hb * wb.z; accb.w += hb * wb.w;
    }
    #pragma unroll
    for (int d = 1; d <= 2; d <<= 1) {
        acca.x += __shfl_xor(acca.x, d); acca.y += __shfl_xor(acca.y, d);
        acca.z += __shfl_xor(acca.z, d); acca.w += __shfl_xor(acca.w, d);
        accb.x += __shfl_xor(accb.x, d); accb.y += __shfl_xor(accb.y, d);
        accb.z += __shfl_xor(accb.z, d); accb.w += __shfl_xor(accb.w, d);
    }
    const int o = lane & 3;
    agg[(size_t)n * DD + lane]      = pick4(acca, o);
    agg[(size_t)n * DD + 64 + lane] = pick4(accb, o);
}

__global__ __launch_bounds__(256) void edge_msg(
    const float* __restrict__ x, const int* __restrict__ esrc,
    const int* __restrict__ edst, const int* __restrict__ etyp,
    const float* __restrict__ enorm, const float* __restrict__ W,
    float* __restrict__ agg)
{
    const int t  = threadIdx.x;
    const int le = t >> 7;
    const int j  = t & 127;
    const int e  = blockIdx.x * 2 + le;
    __shared__ float sh[2][DD];
    sh[le][j] = x[(size_t)esrc[e] * DD + j];
    __syncthreads();
    const int b = j >> 2, o = j & 3;
    const float* wr = W + (size_t)etyp[e] * 512 + b * 16 + o;
    const float4 hv = *(const float4*)&sh[le][b * 4];
    float m = hv.x * wr[0] + hv.y * wr[4] + hv.z * wr[8] + hv.w * wr[12];
    m *= enorm[e];
    atomicAdd(&agg[(size_t)edst[e] * DD + j], m);
}

template<int ACT>
__global__ __launch_bounds__(256) void combine(
    float* __restrict__ out, const float* __restrict__ x,
    const float* __restrict__ prev, const float* __restrict__ tdiff,
    const float* __restrict__ nnorm, const float* __restrict__ lw,
    const float* __restrict__ tw)
{
    const int t = threadIdx.x;
    const int j = t & 127;
    const int r = t >> 7;
    const int base = blockIdx.x * 8;
    __shared__ float sh[8][DD];
    __shared__ float sp[8][DD];
    #pragma unroll
    for (int q = 0; q < 4; ++q) {
        const int m = q * 2 + r;
        const int n = base + m;
        const float decay = __expf(-tdiff[n] * 0.1f);
        sh[m][j] = x[(size_t)n * DD + j];
        sp[m][j] = prev[(size_t)n * DD + j] * decay;
    }
    __syncthreads();
    float acc[4] = {0.f, 0.f, 0.f, 0.f};
    for (int k = 0; k < DD; k += 4) {
        float wl[4], wt[4];
        #pragma unroll
        for (int kk = 0; kk < 4; ++kk) {
            wl[kk] = lw[(size_t)(k + kk) * DD + j];
            wt[kk] = tw[(size_t)(k + kk) * DD + j];
        }
        #pragma unroll
        for (int q = 0; q < 4; ++q) {
            const int m = q * 2 + r;
            const float4 a = *(const float4*)&sh[m][k];
            const float4 p = *(const float4*)&sp[m][k];
            acc[q] += a.x * wl[0] + a.y * wl[1] + a.z * wl[2] + a.w * wl[3]
                    + p.x * wt[0] + p.y * wt[1] + p.z * wt[2] + p.w * wt[3];
        }
    }
    #pragma unroll
    for (int q = 0; q < 4; ++q) {
        const int m = q * 2 + r;
        const int n = base + m;
        float v = out[(size_t)n * DD + j] * nnorm[n] + acc[q];
        if (ACT) v = fmaxf(v, 0.f);
        out[(size_t)n * DD + j] = v;
    }
}

// ---------------------------------------------------------------------------
extern "C" void kernel_launch(void* const* d_in, const int* in_sizes, int n_in,
                              void* d_out, int out_size, void* d_ws, size_t ws_size,
                              hipStream_t stream) {
    const float* h     = (const float*)d_in[0];
    const float* fprev = (const float*)d_in[1];
    const float* sprev = (const float*)d_in[2];
    const float* tdiff = (const float*)d_in[3];
    const int*   esrc  = (const int*)d_in[4];
    const int*   edst  = (const int*)d_in[5];
    const int*   etyp  = (const int*)d_in[6];
    const float* enorm = (const float*)d_in[7];
    const float* nnorm = (const float*)d_in[8];
    const float* W1    = (const float*)d_in[9];
    const float* W2    = (const float*)d_in[10];
    const float* lw1   = (const float*)d_in[11];
    const float* lw2   = (const float*)d_in[12];
    const float* tw1   = (const float*)d_in[13];
    const float* tw2   = (const float*)d_in[14];

    float* h1 = (float*)d_out;
    float* h2 = h1 + (size_t)NN * DD;
    const size_t layer_bytes = (size_t)NN * DD * sizeof(float);

    // ---- carve workspace ----
    char* wsp = (char*)d_ws;
    int*   cnt   = (int*)wsp;  wsp += (size_t)NPAD * 4;
    int*   off   = (int*)wsp;  wsp += (size_t)NPAD * 4;
    int*   cur   = (int*)wsp;  wsp += (size_t)NPAD * 4;
    int*   bsum  = (int*)wsp;  wsp += 256 * 4;
    int4*  sedge = (int4*)wsp; wsp += (size_t)NE * 16;
    const size_t ws_sorted = (size_t)(wsp - (char*)d_ws);
    unsigned short* X1   = (unsigned short*)wsp; wsp += (size_t)NN * 256 * 2;
    unsigned short* X2   = (unsigned short*)wsp; wsp += (size_t)NN * 256 * 2;
    unsigned short* Wc1p = (unsigned short*)wsp; wsp += 4096 * 8 * 2;
    unsigned short* Wc2p = (unsigned short*)wsp; wsp += 4096 * 8 * 2;
    unsigned short* W1b  = (unsigned short*)wsp; wsp += (size_t)460 * 512 * 2;
    unsigned short* W2b  = (unsigned short*)wsp; wsp += (size_t)460 * 512 * 2;
    const size_t ws_full = (size_t)(wsp - (char*)d_ws);

    const int grid_mm = (NN + 63) / 64;   // 782

    if (ws_size >= ws_full) {
        // ---- dst-sort (shared by both layers) ----
        hipMemsetAsync(cnt, 0, (size_t)NPAD * 4, stream);
        k_hist   <<<NE / 256, 256, 0, stream>>>(edst, cnt);
        k_scan_a <<<NBLK_SCAN, 256, 0, stream>>>(cnt, bsum);
        k_scan_b <<<1, 256, 0, stream>>>(bsum);
        k_scan_c <<<NBLK_SCAN, 256, 0, stream>>>(cnt, bsum, off, cur);
        k_scatter<<<NE / 256, 256, 0, stream>>>(esrc, edst, etyp, enorm, cur, sedge);
        // ---- conversions (fused) ----
        conv_x  <<<NN * DD / 256, 256, 0, stream>>>(h, fprev, sprev, tdiff, X1, X2);
        conv_w2 <<<2 * 460 * 512 / 256, 256, 0, stream>>>(W1, W2, W1b, W2b);
        pack_wc2<<<32, 256, 0, stream>>>(lw1, tw1, lw2, tw2, Wc1p, Wc2p);
        // ---- layer 1 ----
        k_agg2<<<NN / 4, 256, 0, stream>>>(X1, sedge, off, W1b, nnorm, h1);
        combine_mfma<0, 1><<<grid_mm, 256, 0, stream>>>(h1, X1, Wc1p, h1, X2);
        // ---- layer 2 ----
        k_agg2<<<NN / 4, 256, 0, stream>>>(X2, sedge, off, W2b, nnorm, h2);
        combine_mfma<1, 0><<<grid_mm, 256, 0, stream>>>(h2, X2, Wc2p, h2, nullptr);
    } else if (ws_size >= ws_sorted) {
        // tier 2: fp32 sorted path
        hipMemsetAsync(cnt, 0, (size_t)NPAD * 4, stream);
        k_hist   <<<NE / 256, 256, 0, stream>>>(edst, cnt);
        k_scan_a <<<NBLK_SCAN, 256, 0, stream>>>(cnt, bsum);
        k_scan_b <<<1, 256, 0, stream>>>(bsum);
        k_scan_c <<<NBLK_SCAN, 256, 0, stream>>>(cnt, bsum, off, cur);
        k_scatter<<<NE / 256, 256, 0, stream>>>(esrc, edst, etyp, enorm, cur, sedge);
        k_agg_t2<<<NN / 4, 256, 0, stream>>>(h, sedge, off, W1, h1);
        combine<0><<<NN / 8, 256, 0, stream>>>(h1, h, fprev, tdiff, nnorm, lw1, tw1);
        k_agg_t2<<<NN / 4, 256, 0, stream>>>(h1, sedge, off, W2, h2);
        combine<1><<<NN / 8, 256, 0, stream>>>(h2, h1, sprev, tdiff, nnorm, lw2, tw2);
    } else {
        // tier 3: atomic path
        hipMemsetAsync(h1, 0, layer_bytes, stream);
        edge_msg<<<NE / 2, 256, 0, stream>>>(h, esrc, edst, etyp, enorm, W1, h1);
        combine<0><<<NN / 8, 256, 0, stream>>>(h1, h, fprev, tdiff, nnorm, lw1, tw1);
        hipMemsetAsync(h2, 0, layer_bytes, stream);
        edge_msg<<<NE / 2, 256, 0, stream>>>(h1, esrc, edst, etyp, enorm, W2, h2);
        combine<1><<<NN / 8, 256, 0, stream>>>(h2, h1, sprev, tdiff, nnorm, lw2, tw2);
    }
}